// Round 2
// baseline (525.491 us; speedup 1.0000x reference)
//
#include <hip/hip_runtime.h>

// Problem: out[h] = concat( x[idx[h,0]], ..., x[idx[h,31]], dis[h,:], angle[h,:] )
// Shapes: x[100000,32] f32, idx[100000,32] i32, dis/angle[100000,32] f32
// Out: [100000, 1088] f32.  Pure gather+concat -> HBM-write-bound (~435 MB out).

constexpr int W = 32;
constexpr int D = 32;
constexpr int ROW = W * D + 2 * W;  // 1088 floats per output row

// clang vector type: valid for __builtin_nontemporal_store (HIP float4 is not)
typedef float f32x4 __attribute__((ext_vector_type(4)));

__global__ __launch_bounds__(256) void idx_gather_concat_kernel(
    const float* __restrict__ x,
    const int* __restrict__ idx,
    const float* __restrict__ dis,
    const float* __restrict__ angle,
    float* __restrict__ out,
    int n)
{
    const int h = blockIdx.x;
    if (h >= n) return;
    const int tid = threadIdx.x;

    const f32x4* __restrict__ xv = (const f32x4*)x;          // x rows: 8 f32x4 each
    f32x4* __restrict__ orow = (f32x4*)(out + (size_t)h * ROW);

    // --- gathered segment: 1024 floats = 256 f32x4, one per thread ---
    // 8 consecutive lanes copy one 128B x-row -> coalesced 16B/lane reads.
    const int w = tid >> 3;        // neighbor index 0..31
    const int e = tid & 7;         // f32x4 index within x row
    const int src = idx[h * W + w];
    const f32x4 v = xv[(size_t)src * (D / 4) + e];
    __builtin_nontemporal_store(v, &orow[tid]);

    // --- tail: dis (32 floats = 8 f32x4) then angle (8 f32x4) ---
    if (tid < 16) {
        const float* srcp = (tid < 8) ? (dis + (size_t)h * W)
                                      : (angle + (size_t)h * W);
        const f32x4 t = ((const f32x4*)srcp)[tid & 7];
        __builtin_nontemporal_store(t, &orow[256 + tid]);
    }
}

extern "C" void kernel_launch(void* const* d_in, const int* in_sizes, int n_in,
                              void* d_out, int out_size, void* d_ws, size_t ws_size,
                              hipStream_t stream)
{
    const float* x     = (const float*)d_in[0];
    const int*   idx   = (const int*)  d_in[1];
    const float* dis   = (const float*)d_in[2];
    const float* angle = (const float*)d_in[3];
    float* out = (float*)d_out;

    const int n = in_sizes[2] / W;  // dis has N*W elements -> N rows

    idx_gather_concat_kernel<<<n, 256, 0, stream>>>(x, idx, dis, angle, out, n);
}